// Round 1
// baseline (280.313 us; speedup 1.0000x reference)
//
#include <hip/hip_runtime.h>
#include <stdint.h>

#define T_SEQ 2048
#define BATCH 2
#define DMODEL 1024
#define NH 16
#define DH 64
#define M_ROWS (T_SEQ * BATCH)   // 4096
#define N_QKV (3 * DMODEL)       // 3072

typedef unsigned short u16;
using bf16x8 = __attribute__((ext_vector_type(8))) __bf16;
using f32x4  = __attribute__((ext_vector_type(4))) float;

__device__ __forceinline__ u16 f2bf(float f) {
    union { float f; uint32_t u; } v; v.f = f;
    uint32_t r = v.u + 0x7fffu + ((v.u >> 16) & 1u);
    return (u16)(r >> 16);
}

// ---------------- pre-pass: fp32 -> bf16 (plain / transposed) ----------------

__global__ void cvt_kernel(const float* __restrict__ in, u16* __restrict__ out, int n) {
    int i = blockIdx.x * 256 + threadIdx.x;
    if (i < n) out[i] = f2bf(in[i]);
}

// in: [R][C] row-major fp32 ; out: [C][R] row-major bf16
__global__ void cvt_t_kernel(const float* __restrict__ in, u16* __restrict__ out, int R, int C) {
    int i = blockIdx.x * 256 + threadIdx.x;
    if (i < R * C) {
        int r = i / C, c = i % C;
        out[c * R + r] = f2bf(in[i]);
    }
}

// ---------------- GEMM: A[M][K] bf16 row-major, Bt[N][K] bf16 row-major ------
// 128x128 block tile, BK=32, 256 threads = 4 waves (2x2), 64x64 per wave.
// EPI 0: scatter to Q/K [BH][T][DH] and V^T [BH][DH][T] (+bias, bf16)
// EPI 1: fp32 out[M][N] (+bias)

template<int EPI>
__global__ __launch_bounds__(256) void gemm_kernel(
    const u16* __restrict__ A, const u16* __restrict__ Bt,
    const float* __restrict__ bias,
    u16* __restrict__ outQ, u16* __restrict__ outK, u16* __restrict__ outV,
    float* __restrict__ outF,
    int M, int N, int K)
{
    __shared__ __align__(16) u16 lA[128 * 32];
    __shared__ __align__(16) u16 lB[128 * 32];

    const int tid  = threadIdx.x;
    const int bm   = blockIdx.y * 128;
    const int bn   = blockIdx.x * 128;
    const int lane = tid & 63;
    const int wid  = tid >> 6;
    const int wm   = (wid >> 1) * 64;
    const int wn   = (wid & 1) * 64;
    const int qr   = lane & 15;
    const int quad = lane >> 4;

    f32x4 acc[4][4];
#pragma unroll
    for (int i = 0; i < 4; i++)
#pragma unroll
        for (int j = 0; j < 4; j++) acc[i][j] = f32x4{0.f, 0.f, 0.f, 0.f};

    const int srow = tid >> 2;        // 0..63
    const int scol = (tid & 3) * 8;   // 0,8,16,24

    for (int k0 = 0; k0 < K; k0 += 32) {
        __syncthreads();
        bf16x8 a0 = *(const bf16x8*)&A [(size_t)(bm + srow)      * K + k0 + scol];
        bf16x8 a1 = *(const bf16x8*)&A [(size_t)(bm + 64 + srow) * K + k0 + scol];
        bf16x8 b0 = *(const bf16x8*)&Bt[(size_t)(bn + srow)      * K + k0 + scol];
        bf16x8 b1 = *(const bf16x8*)&Bt[(size_t)(bn + 64 + srow) * K + k0 + scol];
        *(bf16x8*)&lA[srow * 32 + scol]        = a0;
        *(bf16x8*)&lA[(64 + srow) * 32 + scol] = a1;
        *(bf16x8*)&lB[srow * 32 + scol]        = b0;
        *(bf16x8*)&lB[(64 + srow) * 32 + scol] = b1;
        __syncthreads();

        bf16x8 af[4], bfr[4];
#pragma unroll
        for (int i = 0; i < 4; i++)
            af[i] = *(const bf16x8*)&lA[(wm + i * 16 + qr) * 32 + quad * 8];
#pragma unroll
        for (int j = 0; j < 4; j++)
            bfr[j] = *(const bf16x8*)&lB[(wn + j * 16 + qr) * 32 + quad * 8];
#pragma unroll
        for (int i = 0; i < 4; i++)
#pragma unroll
            for (int j = 0; j < 4; j++)
                acc[i][j] = __builtin_amdgcn_mfma_f32_16x16x32_bf16(af[i], bfr[j], acc[i][j], 0, 0, 0);
    }

#pragma unroll
    for (int i = 0; i < 4; i++) {
#pragma unroll
        for (int j = 0; j < 4; j++) {
            int col = bn + wn + j * 16 + qr;
            float bv = bias[col];
#pragma unroll
            for (int r = 0; r < 4; r++) {
                int row = bm + wm + i * 16 + quad * 4 + r;
                float val = acc[i][j][r] + bv;
                if (EPI == 0) {
                    int t = row >> 1, b = row & 1;
                    int which = col >> 10;      // 0=q 1=k 2=v
                    int dm = col & 1023;
                    int h = dm >> 6, dh = dm & 63;
                    int bh = b * NH + h;
                    u16 u = f2bf(val);
                    if (which == 0)      outQ[((size_t)bh * T_SEQ + t) * DH + dh] = u;
                    else if (which == 1) outK[((size_t)bh * T_SEQ + t) * DH + dh] = u;
                    else                 outV[((size_t)bh * DH + dh) * T_SEQ + t] = u;
                } else {
                    outF[(size_t)row * N + col] = val;
                }
            }
        }
    }
}

// ---------------- flash attention (causal) -----------------------------------
// grid (32 bh, 32 qtiles), 256 thr = 4 waves; wave handles 16 q-rows.
// Q/K: [BH][T][DH] bf16 ; Vt: [BH][DH][T] bf16 ; ctx out: [T*B][D] bf16

__global__ __launch_bounds__(256) void attn_kernel(
    const u16* __restrict__ Qb, const u16* __restrict__ Kb,
    const u16* __restrict__ Vt, u16* __restrict__ ctx)
{
    __shared__ __align__(16) u16 lK[64 * 64];
    __shared__ __align__(16) u16 lV[64 * 64];
    __shared__ __align__(16) u16 lP[4][16 * 64];

    const int bh   = blockIdx.x;
    const int qt   = blockIdx.y;
    const int tid  = threadIdx.x;
    const int lane = tid & 63;
    const int wid  = tid >> 6;
    const int qr   = lane & 15;
    const int quad = lane >> 4;
    const int b    = bh >> 4;
    const int h    = bh & 15;

    const u16* Q  = Qb + (size_t)bh * T_SEQ * DH;
    const u16* Kp = Kb + (size_t)bh * T_SEQ * DH;
    const u16* Vp = Vt + (size_t)bh * DH * T_SEQ;

    const int q0 = qt * 64 + wid * 16;   // wave's first q row

    bf16x8 qf[2];
#pragma unroll
    for (int ks = 0; ks < 2; ks++)
        qf[ks] = *(const bf16x8*)&Q[(size_t)(q0 + qr) * DH + ks * 32 + quad * 8];

    f32x4 o[4];
#pragma unroll
    for (int f = 0; f < 4; f++) o[f] = f32x4{0.f, 0.f, 0.f, 0.f};
    float mrow[4], lrow[4];
#pragma unroll
    for (int r = 0; r < 4; r++) { mrow[r] = -1e30f; lrow[r] = 0.f; }

    const int srow = tid >> 3;        // 0..31
    const int scol = (tid & 7) * 8;   // 0..56

    for (int kt = 0; kt <= qt; kt++) {
        __syncthreads();
        {
            bf16x8 k0v = *(const bf16x8*)&Kp[(size_t)(kt * 64 + srow) * DH + scol];
            bf16x8 k1v = *(const bf16x8*)&Kp[(size_t)(kt * 64 + 32 + srow) * DH + scol];
            bf16x8 v0v = *(const bf16x8*)&Vp[(size_t)srow * T_SEQ + kt * 64 + scol];
            bf16x8 v1v = *(const bf16x8*)&Vp[(size_t)(32 + srow) * T_SEQ + kt * 64 + scol];
            *(bf16x8*)&lK[srow * 64 + scol]        = k0v;
            *(bf16x8*)&lK[(32 + srow) * 64 + scol] = k1v;
            *(bf16x8*)&lV[srow * 64 + scol]        = v0v;
            *(bf16x8*)&lV[(32 + srow) * 64 + scol] = v1v;
        }
        __syncthreads();

        // S = Q K^T  (16 q x 64 key), C-layout frags over key
        f32x4 s[4];
#pragma unroll
        for (int fn = 0; fn < 4; fn++) {
            s[fn] = f32x4{0.f, 0.f, 0.f, 0.f};
#pragma unroll
            for (int ks = 0; ks < 2; ks++) {
                bf16x8 kf = *(const bf16x8*)&lK[(fn * 16 + qr) * 64 + ks * 32 + quad * 8];
                s[fn] = __builtin_amdgcn_mfma_f32_16x16x32_bf16(qf[ks], kf, s[fn], 0, 0, 0);
            }
        }

        // scale + causal mask
#pragma unroll
        for (int fn = 0; fn < 4; fn++) {
            int key = kt * 64 + fn * 16 + qr;
#pragma unroll
            for (int r = 0; r < 4; r++) {
                int qrow = q0 + quad * 4 + r;
                float v = s[fn][r] * 0.125f;
                s[fn][r] = (key <= qrow) ? v : -1e30f;
            }
        }

        // online softmax (rows live across 16 lanes of the quad)
        float alpha[4];
#pragma unroll
        for (int r = 0; r < 4; r++) {
            float v = fmaxf(fmaxf(s[0][r], s[1][r]), fmaxf(s[2][r], s[3][r]));
            v = fmaxf(v, __shfl_xor(v, 1));
            v = fmaxf(v, __shfl_xor(v, 2));
            v = fmaxf(v, __shfl_xor(v, 4));
            v = fmaxf(v, __shfl_xor(v, 8));
            float mn = fmaxf(mrow[r], v);
            alpha[r] = __expf(mrow[r] - mn);
            mrow[r] = mn;
        }
#pragma unroll
        for (int fn = 0; fn < 4; fn++)
#pragma unroll
            for (int r = 0; r < 4; r++)
                s[fn][r] = __expf(s[fn][r] - mrow[r]);
#pragma unroll
        for (int r = 0; r < 4; r++) {
            float v = s[0][r] + s[1][r] + s[2][r] + s[3][r];
            v += __shfl_xor(v, 1);
            v += __shfl_xor(v, 2);
            v += __shfl_xor(v, 4);
            v += __shfl_xor(v, 8);
            lrow[r] = lrow[r] * alpha[r] + v;
#pragma unroll
            for (int f = 0; f < 4; f++) o[f][r] *= alpha[r];
        }

        // P: C-layout -> A-layout via per-wave LDS
#pragma unroll
        for (int fn = 0; fn < 4; fn++)
#pragma unroll
            for (int r = 0; r < 4; r++)
                lP[wid][(quad * 4 + r) * 64 + fn * 16 + qr] = f2bf(s[fn][r]);
        __syncthreads();

        // O += P V   (contract over 64 keys)
#pragma unroll
        for (int f = 0; f < 4; f++) {
#pragma unroll
            for (int ks = 0; ks < 2; ks++) {
                bf16x8 pf = *(const bf16x8*)&lP[wid][qr * 64 + ks * 32 + quad * 8];
                bf16x8 vf = *(const bf16x8*)&lV[(f * 16 + qr) * 64 + ks * 32 + quad * 8];
                o[f] = __builtin_amdgcn_mfma_f32_16x16x32_bf16(pf, vf, o[f], 0, 0, 0);
            }
        }
    }

    // epilogue: ctx[(q*B + b)][h*64 + dh] bf16
#pragma unroll
    for (int f = 0; f < 4; f++) {
#pragma unroll
        for (int r = 0; r < 4; r++) {
            int qrow = q0 + quad * 4 + r;
            int grow = qrow * BATCH + b;
            int col  = h * DH + f * 16 + qr;
            ctx[(size_t)grow * DMODEL + col] = f2bf(o[f][r] / lrow[r]);
        }
    }
}

// ---------------- launch ------------------------------------------------------

extern "C" void kernel_launch(void* const* d_in, const int* in_sizes, int n_in,
                              void* d_out, int out_size, void* d_ws, size_t ws_size,
                              hipStream_t stream) {
    const float* x     = (const float*)d_in[0];
    const float* W_qkv = (const float*)d_in[1];
    const float* b_qkv = (const float*)d_in[2];
    const float* W_out = (const float*)d_in[3];
    const float* b_out = (const float*)d_in[4];
    float* out = (float*)d_out;

    char* ws = (char*)d_ws;
    u16* xb     = (u16*)(ws + 0);                    //  8 MB  [4096][1024]
    u16* wqkv_t = (u16*)(ws + (8u  << 20));          //  6 MB  [3072][1024]
    u16* wout_t = (u16*)(ws + (14u << 20));          //  2 MB  [1024][1024]
    u16* Qb     = (u16*)(ws + (16u << 20));          //  8 MB  [32][2048][64]
    u16* Kb     = (u16*)(ws + (24u << 20));          //  8 MB
    u16* Vt     = (u16*)(ws + (32u << 20));          //  8 MB  [32][64][2048]
    u16* ctx    = xb;  // reuse (xb dead after GEMM1)

    cvt_kernel  <<<(M_ROWS * DMODEL) / 256, 256, 0, stream>>>(x, xb, M_ROWS * DMODEL);
    cvt_t_kernel<<<(DMODEL * N_QKV) / 256, 256, 0, stream>>>(W_qkv, wqkv_t, DMODEL, N_QKV);
    cvt_t_kernel<<<(DMODEL * DMODEL) / 256, 256, 0, stream>>>(W_out, wout_t, DMODEL, DMODEL);

    gemm_kernel<0><<<dim3(N_QKV / 128, M_ROWS / 128), 256, 0, stream>>>(
        xb, wqkv_t, b_qkv, Qb, Kb, Vt, nullptr, M_ROWS, N_QKV, DMODEL);

    attn_kernel<<<dim3(BATCH * NH, T_SEQ / 64), 256, 0, stream>>>(Qb, Kb, Vt, ctx);

    gemm_kernel<1><<<dim3(DMODEL / 128, M_ROWS / 128), 256, 0, stream>>>(
        ctx, wout_t, b_out, nullptr, nullptr, nullptr, out, M_ROWS, DMODEL, DMODEL);
}

// Round 2
// 238.495 us; speedup vs baseline: 1.1753x; 1.1753x over previous
//
#include <hip/hip_runtime.h>
#include <stdint.h>

#define T_SEQ 2048
#define BATCH 2
#define DMODEL 1024
#define NH 16
#define DH 64
#define M_ROWS (T_SEQ * BATCH)   // 4096
#define N_QKV (3 * DMODEL)       // 3072

typedef unsigned short u16;
using bf16x8 = __attribute__((ext_vector_type(8))) __bf16;
using f32x4  = __attribute__((ext_vector_type(4))) float;

__device__ __forceinline__ u16 f2bf(float f) {
    union { float f; uint32_t u; } v; v.f = f;
    uint32_t r = v.u + 0x7fffu + ((v.u >> 16) & 1u);
    return (u16)(r >> 16);
}

// pack two already-bf16-truncated floats into (lo=a, hi=b)
__device__ __forceinline__ uint32_t pack2(float a, float b) {
    union { float f; uint32_t u; } x, y; x.f = a; y.f = b;
    return (x.u >> 16) | (y.u & 0xffff0000u);
}

// async 16B/lane global -> LDS. lds must be wave-uniform; data lands at lds + lane*16.
__device__ __forceinline__ void lds_load16(void* lds, const void* g) {
    auto lp = (__attribute__((address_space(3))) uint32_t*)(uint32_t)(uintptr_t)lds;
    auto gp = (const __attribute__((address_space(1))) uint32_t*)(uintptr_t)g;
    __builtin_amdgcn_global_load_lds(gp, lp, 16, 0, 0);
}

// ---------------- pre-pass: fp32 -> bf16 (plain / transposed) ----------------

__global__ void cvt_kernel(const float* __restrict__ in, u16* __restrict__ out, int n) {
    int i = blockIdx.x * 256 + threadIdx.x;
    if (i < n) out[i] = f2bf(in[i]);
}

__global__ void cvt_t_kernel(const float* __restrict__ in, u16* __restrict__ out, int R, int C) {
    int i = blockIdx.x * 256 + threadIdx.x;
    if (i < R * C) {
        int r = i / C, c = i % C;
        out[c * R + r] = f2bf(in[i]);
    }
}

// ---------------- GEMM: A[M][K] bf16 rm, Bt[N][K] bf16 rm --------------------
// 128x128 tile, BK=32, 4 waves (2x2), 64x64/wave, global_load_lds staging.

template<int EPI>
__global__ __launch_bounds__(256) void gemm_kernel(
    const u16* __restrict__ A, const u16* __restrict__ Bt,
    const float* __restrict__ bias,
    u16* __restrict__ outQ, u16* __restrict__ outK, u16* __restrict__ outV,
    float* __restrict__ outF,
    int M, int N, int K)
{
    __shared__ __align__(16) u16 lA[128 * 32];
    __shared__ __align__(16) u16 lB[128 * 32];

    const int tid  = threadIdx.x;
    const int bm   = blockIdx.y * 128;
    const int bn   = blockIdx.x * 128;
    const int lane = tid & 63;
    const int wid  = tid >> 6;
    const int wm   = (wid >> 1) * 64;
    const int wn   = (wid & 1) * 64;
    const int qr   = lane & 15;
    const int quad = lane >> 4;
    const int r4   = lane >> 2;        // 0..15 row within 16-row chunk
    const int c4   = (lane & 3) * 8;   // u16 col

    f32x4 acc[4][4];
#pragma unroll
    for (int i = 0; i < 4; i++)
#pragma unroll
        for (int j = 0; j < 4; j++) acc[i][j] = f32x4{0.f, 0.f, 0.f, 0.f};

    for (int k0 = 0; k0 < K; k0 += 32) {
        __syncthreads();
        // stage: 8 chunks of 16 rows each for A and B; wave w does chunks w, w+4
#pragma unroll
        for (int cc = 0; cc < 2; cc++) {
            int c = wid + cc * 4;
            lds_load16(&lA[c * 512], &A [(size_t)(bm + 16 * c + r4) * K + k0 + c4]);
            lds_load16(&lB[c * 512], &Bt[(size_t)(bn + 16 * c + r4) * K + k0 + c4]);
        }
        __syncthreads();

        bf16x8 af[4], bfr[4];
#pragma unroll
        for (int i = 0; i < 4; i++)
            af[i] = *(const bf16x8*)&lA[(wm + i * 16 + qr) * 32 + quad * 8];
#pragma unroll
        for (int j = 0; j < 4; j++)
            bfr[j] = *(const bf16x8*)&lB[(wn + j * 16 + qr) * 32 + quad * 8];
#pragma unroll
        for (int i = 0; i < 4; i++)
#pragma unroll
            for (int j = 0; j < 4; j++)
                acc[i][j] = __builtin_amdgcn_mfma_f32_16x16x32_bf16(af[i], bfr[j], acc[i][j], 0, 0, 0);
    }

#pragma unroll
    for (int i = 0; i < 4; i++) {
#pragma unroll
        for (int j = 0; j < 4; j++) {
            int col = bn + wn + j * 16 + qr;
            float bv = bias[col];
#pragma unroll
            for (int r = 0; r < 4; r++) {
                int row = bm + wm + i * 16 + quad * 4 + r;
                float val = acc[i][j][r] + bv;
                if (EPI == 0) {
                    int t = row >> 1, b = row & 1;
                    int which = col >> 10;      // 0=q 1=k 2=v
                    int dm = col & 1023;
                    int h = dm >> 6, dh = dm & 63;
                    int bh = b * NH + h;
                    u16 u = f2bf(val);
                    if (which == 0)      outQ[((size_t)bh * T_SEQ + t) * DH + dh] = u;
                    else if (which == 1) outK[((size_t)bh * T_SEQ + t) * DH + dh] = u;
                    else                 outV[((size_t)bh * DH + dh) * T_SEQ + t] = u;
                } else {
                    outF[(size_t)row * N + col] = val;
                }
            }
        }
    }
}

// ---------------- flash attention (causal), S^T formulation ------------------
// grid (32 bh, 32 qtiles reversed), 256 thr = 4 waves; wave = 16 q-rows.
// Lane owns q = q0 + (lane&15); keys spread over quads.

#define LPS 72   // lP row stride (u16), padded: 144B rows, 16B-aligned

__global__ __launch_bounds__(256) void attn_kernel(
    const u16* __restrict__ Qb, const u16* __restrict__ Kb,
    const u16* __restrict__ Vt, u16* __restrict__ ctx)
{
    __shared__ __align__(16) u16 lK[64 * 64];
    __shared__ __align__(16) u16 lV[64 * 64];
    __shared__ __align__(16) u16 lP[4][16 * LPS];

    const int bh   = blockIdx.x;
    const int qt   = 31 - blockIdx.y;          // long blocks dispatch first
    const int tid  = threadIdx.x;
    const int lane = tid & 63;
    const int wid  = tid >> 6;
    const int qr   = lane & 15;
    const int quad = lane >> 4;
    const int r8   = lane >> 3;                // staging row in 8-row chunk
    const int c8   = (lane & 7) * 8;           // staging u16 col
    const int b    = bh >> 4;
    const int h    = bh & 15;

    const u16* Q  = Qb + (size_t)bh * T_SEQ * DH;
    const u16* Kp = Kb + (size_t)bh * T_SEQ * DH;
    const u16* Vp = Vt + (size_t)bh * DH * T_SEQ;

    const int q0 = qt * 64 + wid * 16;

    bf16x8 qf[2];
#pragma unroll
    for (int ks = 0; ks < 2; ks++)
        qf[ks] = *(const bf16x8*)&Q[(size_t)(q0 + qr) * DH + ks * 32 + quad * 8];

    f32x4 o[4];
#pragma unroll
    for (int f = 0; f < 4; f++) o[f] = f32x4{0.f, 0.f, 0.f, 0.f};
    float m2 = -1e30f, l = 0.f;                // per-lane (one q-row), log2 domain

    const float SC = 0.18033688011112f;        // (1/sqrt(64)) * log2(e)

    for (int kt = 0; kt <= qt; kt++) {
        __syncthreads();
        // async stage K tile [64 keys][64 dh] and V^T tile [64 dh][64 keys]
#pragma unroll
        for (int cc = 0; cc < 2; cc++) {
            int c = wid + cc * 4;              // 8 chunks of 8 rows
            lds_load16(&lK[c * 512], &Kp[(size_t)(kt * 64 + 8 * c + r8) * DH + c8]);
            lds_load16(&lV[c * 512], &Vp[(size_t)(8 * c + r8) * T_SEQ + kt * 64 + c8]);
        }
        __syncthreads();

        // S^T = K Q^T : lane holds S[q = q0+qr][key = kt*64 + fn*16 + quad*4 + r]
        f32x4 s[4];
#pragma unroll
        for (int fn = 0; fn < 4; fn++) {
            s[fn] = f32x4{0.f, 0.f, 0.f, 0.f};
#pragma unroll
            for (int ks = 0; ks < 2; ks++) {
                bf16x8 kf = *(const bf16x8*)&lK[(fn * 16 + qr) * 64 + ks * 32 + quad * 8];
                s[fn] = __builtin_amdgcn_mfma_f32_16x16x32_bf16(kf, qf[ks], s[fn], 0, 0, 0);
            }
        }

        if (kt == qt) {   // diagonal tile: causal mask (uniform branch)
            int qloc = wid * 16 + qr;
#pragma unroll
            for (int fn = 0; fn < 4; fn++)
#pragma unroll
                for (int r = 0; r < 4; r++)
                    s[fn][r] = (fn * 16 + quad * 4 + r <= qloc) ? s[fn][r] * SC : -1e30f;
        } else {
#pragma unroll
            for (int fn = 0; fn < 4; fn++)
#pragma unroll
                for (int r = 0; r < 4; r++) s[fn][r] *= SC;
        }

        // online softmax: in-lane tree + 2 shuffles (quads share q via lane&15)
        float mx = -1e30f;
#pragma unroll
        for (int fn = 0; fn < 4; fn++)
#pragma unroll
            for (int r = 0; r < 4; r++) mx = fmaxf(mx, s[fn][r]);
        mx = fmaxf(mx, __shfl_xor(mx, 16));
        mx = fmaxf(mx, __shfl_xor(mx, 32));
        float mnew  = fmaxf(m2, mx);
        float alpha = exp2f(m2 - mnew);
        m2 = mnew;

        float sum = 0.f;
#pragma unroll
        for (int fn = 0; fn < 4; fn++)
#pragma unroll
            for (int r = 0; r < 4; r++) {
                union { float f; uint32_t u; } p;
                p.f = exp2f(s[fn][r] - m2);
                p.u &= 0xffff0000u;            // truncate to bf16 precision
                s[fn][r] = p.f;                // l uses the SAME rounded value as PV
                sum += p.f;
            }
        sum += __shfl_xor(sum, 16);
        sum += __shfl_xor(sum, 32);
        l = l * alpha + sum;
#pragma unroll
        for (int f = 0; f < 4; f++)
#pragma unroll
            for (int r = 0; r < 4; r++) o[f][r] *= alpha;

        // P -> per-wave LDS (row = q, 4 contiguous keys per fragment), no barrier
#pragma unroll
        for (int fn = 0; fn < 4; fn++) {
            uint2 w; w.x = pack2(s[fn][0], s[fn][1]); w.y = pack2(s[fn][2], s[fn][3]);
            *(uint2*)&lP[wid][qr * LPS + fn * 16 + quad * 4] = w;
        }

        // O^T += V^T P^T
        bf16x8 pf[2];
#pragma unroll
        for (int ks = 0; ks < 2; ks++)
            pf[ks] = *(const bf16x8*)&lP[wid][qr * LPS + ks * 32 + quad * 8];
#pragma unroll
        for (int f = 0; f < 4; f++)
#pragma unroll
            for (int ks = 0; ks < 2; ks++) {
                bf16x8 vf = *(const bf16x8*)&lV[(f * 16 + qr) * 64 + ks * 32 + quad * 8];
                o[f] = __builtin_amdgcn_mfma_f32_16x16x32_bf16(vf, pf[ks], o[f], 0, 0, 0);
            }
    }

    // epilogue: lane owns q = q0+qr, dh = f*16 + quad*4 + r
    float inv = 1.0f / l;
    int q = q0 + qr;
    size_t base = (size_t)(q * BATCH + b) * DMODEL + h * DH;
#pragma unroll
    for (int f = 0; f < 4; f++) {
        float v0 = o[f][0] * inv, v1 = o[f][1] * inv, v2 = o[f][2] * inv, v3 = o[f][3] * inv;
        uint2 w;
        w.x = (uint32_t)f2bf(v0) | ((uint32_t)f2bf(v1) << 16);
        w.y = (uint32_t)f2bf(v2) | ((uint32_t)f2bf(v3) << 16);
        *(uint2*)&ctx[base + f * 16 + quad * 4] = w;
    }
}

// ---------------- launch ------------------------------------------------------

extern "C" void kernel_launch(void* const* d_in, const int* in_sizes, int n_in,
                              void* d_out, int out_size, void* d_ws, size_t ws_size,
                              hipStream_t stream) {
    const float* x     = (const float*)d_in[0];
    const float* W_qkv = (const float*)d_in[1];
    const float* b_qkv = (const float*)d_in[2];
    const float* W_out = (const float*)d_in[3];
    const float* b_out = (const float*)d_in[4];
    float* out = (float*)d_out;

    char* ws = (char*)d_ws;
    u16* xb     = (u16*)(ws + 0);                    //  8 MB  [4096][1024]
    u16* wqkv_t = (u16*)(ws + (8u  << 20));          //  6 MB  [3072][1024]
    u16* wout_t = (u16*)(ws + (14u << 20));          //  2 MB  [1024][1024]
    u16* Qb     = (u16*)(ws + (16u << 20));          //  8 MB  [32][2048][64]
    u16* Kb     = (u16*)(ws + (24u << 20));          //  8 MB
    u16* Vt     = (u16*)(ws + (32u << 20));          //  8 MB  [32][64][2048]
    u16* ctx    = xb;  // reuse (xb dead after GEMM1)

    cvt_kernel  <<<(M_ROWS * DMODEL) / 256, 256, 0, stream>>>(x, xb, M_ROWS * DMODEL);
    cvt_t_kernel<<<(DMODEL * N_QKV) / 256, 256, 0, stream>>>(W_qkv, wqkv_t, DMODEL, N_QKV);
    cvt_t_kernel<<<(DMODEL * DMODEL) / 256, 256, 0, stream>>>(W_out, wout_t, DMODEL, DMODEL);

    gemm_kernel<0><<<dim3(N_QKV / 128, M_ROWS / 128), 256, 0, stream>>>(
        xb, wqkv_t, b_qkv, Qb, Kb, Vt, nullptr, M_ROWS, N_QKV, DMODEL);

    attn_kernel<<<dim3(BATCH * NH, T_SEQ / 64), 256, 0, stream>>>(Qb, Kb, Vt, ctx);

    gemm_kernel<1><<<dim3(DMODEL / 128, M_ROWS / 128), 256, 0, stream>>>(
        ctx, wout_t, b_out, nullptr, nullptr, nullptr, out, M_ROWS, DMODEL, DMODEL);
}

// Round 3
// 224.815 us; speedup vs baseline: 1.2469x; 1.0609x over previous
//
#include <hip/hip_runtime.h>
#include <stdint.h>

#define T_SEQ 2048
#define BATCH 2
#define DMODEL 1024
#define NH 16
#define DH 64
#define M_ROWS (T_SEQ * BATCH)   // 4096
#define N_QKV (3 * DMODEL)       // 3072

typedef unsigned short u16;
using bf16x8 = __attribute__((ext_vector_type(8))) __bf16;
using f32x4  = __attribute__((ext_vector_type(4))) float;

__device__ __forceinline__ u16 f2bf(float f) {
    union { float f; uint32_t u; } v; v.f = f;
    uint32_t r = v.u + 0x7fffu + ((v.u >> 16) & 1u);
    return (u16)(r >> 16);
}

__device__ __forceinline__ uint32_t pack2(float a, float b) {
    union { float f; uint32_t u; } x, y; x.f = a; y.f = b;
    return (x.u >> 16) | (y.u & 0xffff0000u);
}

// async 16B/lane global -> LDS; lds base wave-uniform, lane data lands at +lane*16
__device__ __forceinline__ void lds_load16(void* lds, const void* g) {
    auto lp = (__attribute__((address_space(3))) uint32_t*)(uint32_t)(uintptr_t)lds;
    auto gp = (const __attribute__((address_space(1))) uint32_t*)(uintptr_t)g;
    __builtin_amdgcn_global_load_lds(gp, lp, 16, 0, 0);
}

// ---------------- pre-pass ----------------------------------------------------

__global__ void cvt4_kernel(const float* __restrict__ in, u16* __restrict__ out, int n4) {
    int i = blockIdx.x * 256 + threadIdx.x;
    if (i < n4) {
        float4 v = ((const float4*)in)[i];
        union { u16 u[4]; uint2 d; } o;
        o.u[0] = f2bf(v.x); o.u[1] = f2bf(v.y); o.u[2] = f2bf(v.z); o.u[3] = f2bf(v.w);
        ((uint2*)out)[i] = o.d;
    }
}

// in: [R][C] fp32 -> out: [C][R] bf16, LDS-tiled (coalesced both sides)
__global__ void cvt_t_kernel(const float* __restrict__ in, u16* __restrict__ out, int R, int C) {
    __shared__ float t[32][33];
    int bx = blockIdx.x * 32;   // col tile
    int by = blockIdx.y * 32;   // row tile
    int tx = threadIdx.x & 31, ty = threadIdx.x >> 5;   // 8 rows/pass
#pragma unroll
    for (int rr = 0; rr < 32; rr += 8)
        t[ty + rr][tx] = in[(size_t)(by + ty + rr) * C + bx + tx];
    __syncthreads();
#pragma unroll
    for (int rr = 0; rr < 32; rr += 8)
        out[(size_t)(bx + ty + rr) * R + by + tx] = f2bf(t[tx][ty + rr]);
}

// ---------------- GEMM: A[M][K] bf16 rm, Bt[N][K] bf16 rm --------------------
// 128x128 tile, BK=32, 4 waves (2x2), 64x64/wave, global_load_lds staging,
// XOR chunk-swizzle: physical 16B chunk = logical ^ ((row>>1)&3)

template<int EPI>
__global__ __launch_bounds__(256) void gemm_kernel(
    const u16* __restrict__ A, const u16* __restrict__ Bt,
    const float* __restrict__ bias,
    u16* __restrict__ outQ, u16* __restrict__ outK, u16* __restrict__ outV,
    float* __restrict__ outF,
    int M, int N, int K)
{
    __shared__ __align__(16) u16 lA[128 * 32];
    __shared__ __align__(16) u16 lB[128 * 32];

    const int tid  = threadIdx.x;
    const int bm   = blockIdx.y * 128;
    const int bn   = blockIdx.x * 128;
    const int lane = tid & 63;
    const int wid  = tid >> 6;
    const int wm   = (wid >> 1) * 64;
    const int wn   = (wid & 1) * 64;
    const int qr   = lane & 15;
    const int quad = lane >> 4;
    const int r4   = lane >> 2;                                  // staging row 0..15
    const int c4   = (((lane & 3) ^ ((r4 >> 1) & 3))) * 8;       // swizzled src col (u16)
    const int sw   = (qr >> 1) & 3;                              // fragment-read swizzle

    f32x4 acc[4][4];
#pragma unroll
    for (int i = 0; i < 4; i++)
#pragma unroll
        for (int j = 0; j < 4; j++) acc[i][j] = f32x4{0.f, 0.f, 0.f, 0.f};

    for (int k0 = 0; k0 < K; k0 += 32) {
        __syncthreads();
#pragma unroll
        for (int cc = 0; cc < 2; cc++) {
            int c = wid + cc * 4;    // 8 chunks of 16 rows
            lds_load16(&lA[c * 512], &A [(size_t)(bm + 16 * c + r4) * K + k0 + c4]);
            lds_load16(&lB[c * 512], &Bt[(size_t)(bn + 16 * c + r4) * K + k0 + c4]);
        }
        __syncthreads();

        bf16x8 af[4], bfr[4];
#pragma unroll
        for (int i = 0; i < 4; i++)
            af[i] = *(const bf16x8*)&lA[(wm + i * 16 + qr) * 32 + ((quad ^ sw) * 8)];
#pragma unroll
        for (int j = 0; j < 4; j++)
            bfr[j] = *(const bf16x8*)&lB[(wn + j * 16 + qr) * 32 + ((quad ^ sw) * 8)];
#pragma unroll
        for (int i = 0; i < 4; i++)
#pragma unroll
            for (int j = 0; j < 4; j++)
                acc[i][j] = __builtin_amdgcn_mfma_f32_16x16x32_bf16(af[i], bfr[j], acc[i][j], 0, 0, 0);
    }

#pragma unroll
    for (int i = 0; i < 4; i++) {
#pragma unroll
        for (int j = 0; j < 4; j++) {
            int col = bn + wn + j * 16 + qr;
            float bv = bias[col];
#pragma unroll
            for (int r = 0; r < 4; r++) {
                int row = bm + wm + i * 16 + quad * 4 + r;
                float val = acc[i][j][r] + bv;
                if (EPI == 0) {
                    int t = row >> 1, b = row & 1;
                    int which = col >> 10;      // 0=q 1=k 2=v
                    int dm = col & 1023;
                    int h = dm >> 6, dh = dm & 63;
                    int bh = b * NH + h;
                    u16 u = f2bf(val);
                    if (which == 0)      outQ[((size_t)bh * T_SEQ + t) * DH + dh] = u;
                    else if (which == 1) outK[((size_t)bh * T_SEQ + t) * DH + dh] = u;
                    else                 outV[((size_t)bh * DH + dh) * T_SEQ + t] = u;
                } else {
                    outF[(size_t)row * N + col] = val;
                }
            }
        }
    }
}

// ---------------- flash attention (causal), S^T form, swizzled LDS ----------
// grid (32 bh, 16 qtiles reversed), 256 thr = 4 waves; wave = 32 q-rows (2 groups).
// Lane owns q = q0 + g*16 + (lane&15); keys spread over quads.
// LDS 16B-chunk swizzle: physical = logical ^ (row&7).

__global__ __launch_bounds__(256) void attn_kernel(
    const u16* __restrict__ Qb, const u16* __restrict__ Kb,
    const u16* __restrict__ Vt, u16* __restrict__ ctx)
{
    __shared__ __align__(16) u16 lK[64 * 64];       // [key][dh]
    __shared__ __align__(16) u16 lV[64 * 64];       // [dh][key]
    __shared__ __align__(16) u16 lP[4][32 * 64];    // per-wave [q][key]

    const int bh   = blockIdx.x;
    const int qt   = 15 - blockIdx.y;               // long blocks first
    const int tid  = threadIdx.x;
    const int lane = tid & 63;
    const int wid  = tid >> 6;
    const int qr   = lane & 15;
    const int quad = lane >> 4;
    const int b    = bh >> 4;
    const int h    = bh & 15;
    const int sw   = qr & 7;                        // fragment-read swizzle

    const int srow = wid * 8 + (lane >> 3);                         // staging row
    const int scol = (((lane & 7) ^ ((lane >> 3) & 7))) * 8;        // swizzled src col

    const u16* Q  = Qb + (size_t)bh * T_SEQ * DH;
    const u16* Kp = Kb + (size_t)bh * T_SEQ * DH;
    const u16* Vp = Vt + (size_t)bh * DH * T_SEQ;

    const int q0 = qt * 128 + wid * 32;             // wave's first q row

    bf16x8 qf[2][2];
#pragma unroll
    for (int g = 0; g < 2; g++)
#pragma unroll
        for (int ks = 0; ks < 2; ks++)
            qf[g][ks] = *(const bf16x8*)&Q[(size_t)(q0 + g * 16 + qr) * DH + ks * 32 + quad * 8];

    f32x4 o[2][4];
#pragma unroll
    for (int g = 0; g < 2; g++)
#pragma unroll
        for (int f = 0; f < 4; f++) o[g][f] = f32x4{0.f, 0.f, 0.f, 0.f};
    float m2[2] = {-1e30f, -1e30f}, l[2] = {0.f, 0.f};

    const float SC = 0.18033688011112f;             // (1/sqrt(64)) * log2(e)
    const int ktEnd = 2 * qt + 2;

    for (int kt = 0; kt < ktEnd; kt++) {
        __syncthreads();
#pragma unroll
        for (int half = 0; half < 2; half++) {
            lds_load16(&lK[half * 2048 + wid * 512],
                       &Kp[(size_t)(kt * 64 + half * 32 + srow) * DH + scol]);
            lds_load16(&lV[half * 2048 + wid * 512],
                       &Vp[(size_t)(half * 32 + srow) * T_SEQ + kt * 64 + scol]);
        }
        __syncthreads();

        if (kt * 64 > q0 + 31) continue;            // fully masked for this wave (uniform)

        // S^T = K Q^T : s[g][fn][r] = S[q = q0+g*16+qr][key = kt*64 + fn*16 + quad*4 + r]
        f32x4 s[2][4];
#pragma unroll
        for (int g = 0; g < 2; g++)
#pragma unroll
            for (int fn = 0; fn < 4; fn++) s[g][fn] = f32x4{0.f, 0.f, 0.f, 0.f};
#pragma unroll
        for (int fn = 0; fn < 4; fn++)
#pragma unroll
            for (int ks = 0; ks < 2; ks++) {
                bf16x8 kf = *(const bf16x8*)&lK[(fn * 16 + qr) * 64 + (((ks * 4 + quad) ^ sw) * 8)];
#pragma unroll
                for (int g = 0; g < 2; g++)
                    s[g][fn] = __builtin_amdgcn_mfma_f32_16x16x32_bf16(kf, qf[g][ks], s[g][fn], 0, 0, 0);
            }

        // scale + causal mask
        if (kt * 64 + 63 <= q0) {                   // fully unmasked (uniform)
#pragma unroll
            for (int g = 0; g < 2; g++)
#pragma unroll
                for (int fn = 0; fn < 4; fn++)
#pragma unroll
                    for (int r = 0; r < 4; r++) s[g][fn][r] *= SC;
        } else {
#pragma unroll
            for (int g = 0; g < 2; g++) {
                int q = q0 + g * 16 + qr;
#pragma unroll
                for (int fn = 0; fn < 4; fn++) {
                    int key = kt * 64 + fn * 16 + quad * 4;
#pragma unroll
                    for (int r = 0; r < 4; r++)
                        s[g][fn][r] = (key + r <= q) ? s[g][fn][r] * SC : -1e30f;
                }
            }
        }

        // online softmax per group (row = lane, 2 shuffles for cross-quad reduce)
#pragma unroll
        for (int g = 0; g < 2; g++) {
            float mx = -1e30f;
#pragma unroll
            for (int fn = 0; fn < 4; fn++)
#pragma unroll
                for (int r = 0; r < 4; r++) mx = fmaxf(mx, s[g][fn][r]);
            mx = fmaxf(mx, __shfl_xor(mx, 16));
            mx = fmaxf(mx, __shfl_xor(mx, 32));
            float mnew  = fmaxf(m2[g], mx);
            float alpha = exp2f(m2[g] - mnew);
            m2[g] = mnew;

            float sum = 0.f;
#pragma unroll
            for (int fn = 0; fn < 4; fn++)
#pragma unroll
                for (int r = 0; r < 4; r++) {
                    union { float f; uint32_t u; } p;
                    p.f = exp2f(s[g][fn][r] - m2[g]);
                    p.u &= 0xffff0000u;             // match bf16 P used in PV
                    s[g][fn][r] = p.f;
                    sum += p.f;
                }
            sum += __shfl_xor(sum, 16);
            sum += __shfl_xor(sum, 32);
            l[g] = l[g] * alpha + sum;
#pragma unroll
            for (int f = 0; f < 4; f++)
#pragma unroll
                for (int r = 0; r < 4; r++) o[g][f][r] *= alpha;

            // P -> per-wave LDS, swizzled (8B halves of 16B chunks), no barrier
#pragma unroll
            for (int fn = 0; fn < 4; fn++) {
                uint2 w; w.x = pack2(s[g][fn][0], s[g][fn][1]); w.y = pack2(s[g][fn][2], s[g][fn][3]);
                int phys = ((fn * 2 + (quad >> 1)) ^ sw);
                *(uint2*)&lP[wid][(g * 16 + qr) * 64 + phys * 8 + (quad & 1) * 4] = w;
            }
        }

        // O^T += V^T P^T
        bf16x8 pf[2][2];
#pragma unroll
        for (int g = 0; g < 2; g++)
#pragma unroll
            for (int ks = 0; ks < 2; ks++)
                pf[g][ks] = *(const bf16x8*)&lP[wid][(g * 16 + qr) * 64 + (((ks * 4 + quad) ^ sw) * 8)];
#pragma unroll
        for (int f = 0; f < 4; f++)
#pragma unroll
            for (int ks = 0; ks < 2; ks++) {
                bf16x8 vf = *(const bf16x8*)&lV[(f * 16 + qr) * 64 + (((ks * 4 + quad) ^ sw) * 8)];
#pragma unroll
                for (int g = 0; g < 2; g++)
                    o[g][f] = __builtin_amdgcn_mfma_f32_16x16x32_bf16(vf, pf[g][ks], o[g][f], 0, 0, 0);
            }
    }

    // epilogue: lane owns q = q0 + g*16 + qr, dh = f*16 + quad*4 + r
#pragma unroll
    for (int g = 0; g < 2; g++) {
        float inv = 1.0f / l[g];
        int q = q0 + g * 16 + qr;
        size_t base = (size_t)(q * BATCH + b) * DMODEL + h * DH;
#pragma unroll
        for (int f = 0; f < 4; f++) {
            uint2 w;
            w.x = (uint32_t)f2bf(o[g][f][0] * inv) | ((uint32_t)f2bf(o[g][f][1] * inv) << 16);
            w.y = (uint32_t)f2bf(o[g][f][2] * inv) | ((uint32_t)f2bf(o[g][f][3] * inv) << 16);
            *(uint2*)&ctx[base + f * 16 + quad * 4] = w;
        }
    }
}

// ---------------- launch ------------------------------------------------------

extern "C" void kernel_launch(void* const* d_in, const int* in_sizes, int n_in,
                              void* d_out, int out_size, void* d_ws, size_t ws_size,
                              hipStream_t stream) {
    const float* x     = (const float*)d_in[0];
    const float* W_qkv = (const float*)d_in[1];
    const float* b_qkv = (const float*)d_in[2];
    const float* W_out = (const float*)d_in[3];
    const float* b_out = (const float*)d_in[4];
    float* out = (float*)d_out;

    char* ws = (char*)d_ws;
    u16* xb     = (u16*)(ws + 0);                    //  8 MB  [4096][1024]
    u16* wqkv_t = (u16*)(ws + (8u  << 20));          //  6 MB  [3072][1024]
    u16* wout_t = (u16*)(ws + (14u << 20));          //  2 MB  [1024][1024]
    u16* Qb     = (u16*)(ws + (16u << 20));          //  8 MB  [32][2048][64]
    u16* Kb     = (u16*)(ws + (24u << 20));          //  8 MB
    u16* Vt     = (u16*)(ws + (32u << 20));          //  8 MB  [32][64][2048]
    u16* ctx    = xb;  // reuse (xb dead after GEMM1)

    cvt4_kernel <<<(M_ROWS * DMODEL / 4) / 256, 256, 0, stream>>>(x, xb, M_ROWS * DMODEL / 4);
    cvt_t_kernel<<<dim3(N_QKV / 32, DMODEL / 32), 256, 0, stream>>>(W_qkv, wqkv_t, DMODEL, N_QKV);
    cvt_t_kernel<<<dim3(DMODEL / 32, DMODEL / 32), 256, 0, stream>>>(W_out, wout_t, DMODEL, DMODEL);

    gemm_kernel<0><<<dim3(N_QKV / 128, M_ROWS / 128), 256, 0, stream>>>(
        xb, wqkv_t, b_qkv, Qb, Kb, Vt, nullptr, M_ROWS, N_QKV, DMODEL);

    attn_kernel<<<dim3(BATCH * NH, T_SEQ / 128), 256, 0, stream>>>(Qb, Kb, Vt, ctx);

    gemm_kernel<1><<<dim3(DMODEL / 128, M_ROWS / 128), 256, 0, stream>>>(
        ctx, wout_t, b_out, nullptr, nullptr, nullptr, out, M_ROWS, DMODEL, DMODEL);
}

// Round 4
// 218.382 us; speedup vs baseline: 1.2836x; 1.0295x over previous
//
#include <hip/hip_runtime.h>
#include <stdint.h>

#define T_SEQ 2048
#define BATCH 2
#define DMODEL 1024
#define NH 16
#define DH 64
#define M_ROWS (T_SEQ * BATCH)   // 4096
#define N_QKV (3 * DMODEL)       // 3072
#define BHQ (32 * T_SEQ)         // 65536 rows per segment

typedef unsigned short u16;
using bf16x8 = __attribute__((ext_vector_type(8))) __bf16;
using f32x4  = __attribute__((ext_vector_type(4))) float;

__device__ __forceinline__ u16 f2bf(float f) {
    union { float f; uint32_t u; } v; v.f = f;
    uint32_t r = v.u + 0x7fffu + ((v.u >> 16) & 1u);
    return (u16)(r >> 16);
}

__device__ __forceinline__ uint32_t pack2(float a, float b) {
    union { float f; uint32_t u; } x, y; x.f = a; y.f = b;
    return (x.u >> 16) | (y.u & 0xffff0000u);
}

__device__ __forceinline__ float bf2f(u16 u) {
    union { uint32_t u; float f; } v; v.u = (uint32_t)u << 16;
    return v.f;
}

// async 16B/lane global -> LDS; lds base wave-uniform, lane data lands at +lane*16
__device__ __forceinline__ void lds_load16(void* lds, const void* g) {
    auto lp = (__attribute__((address_space(3))) uint32_t*)(uint32_t)(uintptr_t)lds;
    auto gp = (const __attribute__((address_space(1))) uint32_t*)(uintptr_t)g;
    __builtin_amdgcn_global_load_lds(gp, lp, 16, 0, 0);
}

#define SCQ 0.18033688011112f    // (1/sqrt(64)) * log2(e), folded into Q at GEMM1

// ---------------- pre-pass ----------------------------------------------------

__global__ void cvt4_kernel(const float* __restrict__ in, u16* __restrict__ out, int n4) {
    int i = blockIdx.x * 256 + threadIdx.x;
    if (i < n4) {
        float4 v = ((const float4*)in)[i];
        union { u16 u[4]; uint2 d; } o;
        o.u[0] = f2bf(v.x); o.u[1] = f2bf(v.y); o.u[2] = f2bf(v.z); o.u[3] = f2bf(v.w);
        ((uint2*)out)[i] = o.d;
    }
}

// in: [R][C] fp32 -> out: [C][R] bf16, LDS-tiled (coalesced both sides)
__global__ void cvt_t_kernel(const float* __restrict__ in, u16* __restrict__ out, int R, int C) {
    __shared__ float t[32][33];
    int bx = blockIdx.x * 32;
    int by = blockIdx.y * 32;
    int tx = threadIdx.x & 31, ty = threadIdx.x >> 5;
#pragma unroll
    for (int rr = 0; rr < 32; rr += 8)
        t[ty + rr][tx] = in[(size_t)(by + ty + rr) * C + bx + tx];
    __syncthreads();
#pragma unroll
    for (int rr = 0; rr < 32; rr += 8)
        out[(size_t)(bx + ty + rr) * R + by + tx] = f2bf(t[tx][ty + rr]);
}

// ---------------- GEMM: A[M][K] bf16 rm, Bt[N][K] bf16 rm --------------------
// 128x128 tile, BK=32, 4 waves (2x2), 64x64/wave, global_load_lds staging,
// XOR chunk-swizzle: physical 16B chunk = logical ^ ((row>>1)&3)

template<int EPI>
__global__ __launch_bounds__(256) void gemm_kernel(
    const u16* __restrict__ A, const u16* __restrict__ Bt,
    const float* __restrict__ bias,
    u16* __restrict__ outQ, u16* __restrict__ outK, u16* __restrict__ outV,
    float* __restrict__ outF,
    int M, int N, int K)
{
    __shared__ __align__(16) u16 lA[128 * 32];
    __shared__ __align__(16) u16 lB[128 * 32];

    const int tid  = threadIdx.x;
    const int bm   = blockIdx.y * 128;
    const int bn   = blockIdx.x * 128;
    const int lane = tid & 63;
    const int wid  = tid >> 6;
    const int wm   = (wid >> 1) * 64;
    const int wn   = (wid & 1) * 64;
    const int qr   = lane & 15;
    const int quad = lane >> 4;
    const int r4   = lane >> 2;
    const int c4   = (((lane & 3) ^ ((r4 >> 1) & 3))) * 8;
    const int sw   = (qr >> 1) & 3;

    f32x4 acc[4][4];
#pragma unroll
    for (int i = 0; i < 4; i++)
#pragma unroll
        for (int j = 0; j < 4; j++) acc[i][j] = f32x4{0.f, 0.f, 0.f, 0.f};

    for (int k0 = 0; k0 < K; k0 += 32) {
        __syncthreads();
#pragma unroll
        for (int cc = 0; cc < 2; cc++) {
            int c = wid + cc * 4;
            lds_load16(&lA[c * 512], &A [(size_t)(bm + 16 * c + r4) * K + k0 + c4]);
            lds_load16(&lB[c * 512], &Bt[(size_t)(bn + 16 * c + r4) * K + k0 + c4]);
        }
        __syncthreads();

        bf16x8 af[4], bfr[4];
#pragma unroll
        for (int i = 0; i < 4; i++)
            af[i] = *(const bf16x8*)&lA[(wm + i * 16 + qr) * 32 + ((quad ^ sw) * 8)];
#pragma unroll
        for (int j = 0; j < 4; j++)
            bfr[j] = *(const bf16x8*)&lB[(wn + j * 16 + qr) * 32 + ((quad ^ sw) * 8)];
#pragma unroll
        for (int i = 0; i < 4; i++)
#pragma unroll
            for (int j = 0; j < 4; j++)
                acc[i][j] = __builtin_amdgcn_mfma_f32_16x16x32_bf16(af[i], bfr[j], acc[i][j], 0, 0, 0);
    }

#pragma unroll
    for (int i = 0; i < 4; i++) {
#pragma unroll
        for (int j = 0; j < 4; j++) {
            int col = bn + wn + j * 16 + qr;
            float bv = bias[col];
#pragma unroll
            for (int r = 0; r < 4; r++) {
                int row = bm + wm + i * 16 + quad * 4 + r;
                float val = acc[i][j][r] + bv;
                if (EPI == 0) {
                    int t = row >> 1, b = row & 1;
                    int which = col >> 10;      // 0=q 1=k 2=v
                    int dm = col & 1023;
                    int h = dm >> 6, dh = dm & 63;
                    int bh = b * NH + h;
                    if (which == 0) {
                        // fold softmax scale (incl. log2e) into Q
                        outQ[((size_t)bh * T_SEQ + t) * DH + dh] = f2bf(val * SCQ);
                    } else if (which == 1) {
                        outK[((size_t)bh * T_SEQ + t) * DH + dh] = f2bf(val);
                    } else {
                        outV[((size_t)bh * DH + dh) * T_SEQ + t] = f2bf(val);
                    }
                } else {
                    outF[(size_t)row * N + col] = val;
                }
            }
        }
    }
}

// ---------------- flash attention (causal), S^T form, KV-split ---------------
// grid (32 bh, 16 qt reversed, 2 seg), 256 thr = 4 waves; wave = 32 q-rows.
// seg0: kt in [0, qt+1); seg1: kt in [qt+1, 2qt+2)  (equal work).
// Writes unnormalized partial O (bf16) + per-row m,l; merge_kernel combines.
// LDS 16B-chunk swizzle: physical = logical ^ (row&7).

__global__ __launch_bounds__(256) void attn_kernel(
    const u16* __restrict__ Qb, const u16* __restrict__ Kb,
    const u16* __restrict__ Vt,
    u16* __restrict__ Op, float* __restrict__ Mp, float* __restrict__ Lp)
{
    __shared__ __align__(16) u16 lK[64 * 64];       // [key][dh]
    __shared__ __align__(16) u16 lV[64 * 64];       // [dh][key]
    __shared__ __align__(16) u16 lP[4][32 * 64];    // per-wave [q][key]

    const int bh   = blockIdx.x;
    const int qt   = 15 - blockIdx.y;               // long blocks first
    const int seg  = blockIdx.z;
    const int tid  = threadIdx.x;
    const int lane = tid & 63;
    const int wid  = tid >> 6;
    const int qr   = lane & 15;
    const int quad = lane >> 4;
    const int sw   = qr & 7;

    const int srow = wid * 8 + (lane >> 3);
    const int scol = (((lane & 7) ^ ((lane >> 3) & 7))) * 8;

    const u16* Q  = Qb + (size_t)bh * T_SEQ * DH;
    const u16* Kp = Kb + (size_t)bh * T_SEQ * DH;
    const u16* Vp = Vt + (size_t)bh * DH * T_SEQ;

    const int q0 = qt * 128 + wid * 32;

    bf16x8 qf[2][2];
#pragma unroll
    for (int g = 0; g < 2; g++)
#pragma unroll
        for (int ks = 0; ks < 2; ks++)
            qf[g][ks] = *(const bf16x8*)&Q[(size_t)(q0 + g * 16 + qr) * DH + ks * 32 + quad * 8];

    f32x4 o[2][4];
#pragma unroll
    for (int g = 0; g < 2; g++)
#pragma unroll
        for (int f = 0; f < 4; f++) o[g][f] = f32x4{0.f, 0.f, 0.f, 0.f};
    float m2[2] = {-1e30f, -1e30f}, l[2] = {0.f, 0.f};

    const int kt0 = seg ? qt + 1 : 0;
    const int kt1 = seg ? 2 * qt + 2 : qt + 1;

    for (int kt = kt0; kt < kt1; kt++) {
        __syncthreads();
#pragma unroll
        for (int half = 0; half < 2; half++) {
            lds_load16(&lK[half * 2048 + wid * 512],
                       &Kp[(size_t)(kt * 64 + half * 32 + srow) * DH + scol]);
            lds_load16(&lV[half * 2048 + wid * 512],
                       &Vp[(size_t)(half * 32 + srow) * T_SEQ + kt * 64 + scol]);
        }
        __syncthreads();

        if (kt * 64 > q0 + 31) continue;            // fully masked for this wave (staging done)

        // S^T = K Q^T : s[g][fn][r] = S[q = q0+g*16+qr][key = kt*64 + fn*16 + quad*4 + r]
        f32x4 s[2][4];
#pragma unroll
        for (int g = 0; g < 2; g++)
#pragma unroll
            for (int fn = 0; fn < 4; fn++) s[g][fn] = f32x4{0.f, 0.f, 0.f, 0.f};
#pragma unroll
        for (int fn = 0; fn < 4; fn++)
#pragma unroll
            for (int ks = 0; ks < 2; ks++) {
                bf16x8 kf = *(const bf16x8*)&lK[(fn * 16 + qr) * 64 + (((ks * 4 + quad) ^ sw) * 8)];
#pragma unroll
                for (int g = 0; g < 2; g++)
                    s[g][fn] = __builtin_amdgcn_mfma_f32_16x16x32_bf16(kf, qf[g][ks], s[g][fn], 0, 0, 0);
            }

        // causal mask only near the diagonal (scale already folded into Q)
        if (kt * 64 + 63 > q0) {
#pragma unroll
            for (int g = 0; g < 2; g++) {
                int q = q0 + g * 16 + qr;
#pragma unroll
                for (int fn = 0; fn < 4; fn++) {
                    int key = kt * 64 + fn * 16 + quad * 4;
#pragma unroll
                    for (int r = 0; r < 4; r++)
                        if (key + r > q) s[g][fn][r] = -1e30f;
                }
            }
        }

        // online softmax per group (log2 domain; 2 shuffles per reduce)
#pragma unroll
        for (int g = 0; g < 2; g++) {
            float mx = -1e30f;
#pragma unroll
            for (int fn = 0; fn < 4; fn++)
#pragma unroll
                for (int r = 0; r < 4; r++) mx = fmaxf(mx, s[g][fn][r]);
            mx = fmaxf(mx, __shfl_xor(mx, 16));
            mx = fmaxf(mx, __shfl_xor(mx, 32));
            float mnew  = fmaxf(m2[g], mx);
            float alpha = exp2f(m2[g] - mnew);
            m2[g] = mnew;

            float sum = 0.f;
#pragma unroll
            for (int fn = 0; fn < 4; fn++)
#pragma unroll
                for (int r = 0; r < 4; r++) {
                    union { float f; uint32_t u; } p;
                    p.f = exp2f(s[g][fn][r] - m2[g]);
                    p.u &= 0xffff0000u;             // match bf16 P used in PV
                    s[g][fn][r] = p.f;
                    sum += p.f;
                }
            sum += __shfl_xor(sum, 16);
            sum += __shfl_xor(sum, 32);
            l[g] = l[g] * alpha + sum;
#pragma unroll
            for (int f = 0; f < 4; f++)
#pragma unroll
                for (int r = 0; r < 4; r++) o[g][f][r] *= alpha;

            // P -> per-wave LDS, swizzled (8B halves of 16B chunks), no barrier
#pragma unroll
            for (int fn = 0; fn < 4; fn++) {
                uint2 w; w.x = pack2(s[g][fn][0], s[g][fn][1]); w.y = pack2(s[g][fn][2], s[g][fn][3]);
                int phys = ((fn * 2 + (quad >> 1)) ^ sw);
                *(uint2*)&lP[wid][(g * 16 + qr) * 64 + phys * 8 + (quad & 1) * 4] = w;
            }
        }

        // O^T += V^T P^T
        bf16x8 pf[2][2];
#pragma unroll
        for (int g = 0; g < 2; g++)
#pragma unroll
            for (int ks = 0; ks < 2; ks++)
                pf[g][ks] = *(const bf16x8*)&lP[wid][(g * 16 + qr) * 64 + (((ks * 4 + quad) ^ sw) * 8)];
#pragma unroll
        for (int f = 0; f < 4; f++)
#pragma unroll
            for (int ks = 0; ks < 2; ks++) {
                bf16x8 vf = *(const bf16x8*)&lV[(f * 16 + qr) * 64 + (((ks * 4 + quad) ^ sw) * 8)];
#pragma unroll
                for (int g = 0; g < 2; g++)
                    o[g][f] = __builtin_amdgcn_mfma_f32_16x16x32_bf16(vf, pf[g][ks], o[g][f], 0, 0, 0);
            }
    }

    // epilogue: unnormalized partial O (bf16) + m,l per row
#pragma unroll
    for (int g = 0; g < 2; g++) {
        int q = q0 + g * 16 + qr;
        size_t rbase = (size_t)seg * BHQ + (size_t)bh * T_SEQ + q;
        if (quad == 0) { Mp[rbase] = m2[g]; Lp[rbase] = l[g]; }
#pragma unroll
        for (int f = 0; f < 4; f++) {
            uint2 w;
            w.x = (uint32_t)f2bf(o[g][f][0]) | ((uint32_t)f2bf(o[g][f][1]) << 16);
            w.y = (uint32_t)f2bf(o[g][f][2]) | ((uint32_t)f2bf(o[g][f][3]) << 16);
            *(uint2*)&Op[rbase * 64 + f * 16 + quad * 4] = w;
        }
    }
}

// ---------------- merge partials -> ctx --------------------------------------

__global__ void merge_kernel(const u16* __restrict__ Op, const float* __restrict__ Mp,
                             const float* __restrict__ Lp, u16* __restrict__ ctx)
{
    int idx = blockIdx.x * 256 + threadIdx.x;       // over 65536*16 uint2 groups
    int fq  = idx & 15;
    int q   = (idx >> 4) & (T_SEQ - 1);
    int bh  = idx >> 15;
    int b = bh >> 4, h = bh & 15;
    size_t rbase = (size_t)bh * T_SEQ + q;

    float m0 = Mp[rbase], m1 = Mp[rbase + BHQ];
    float l0 = Lp[rbase], l1 = Lp[rbase + BHQ];
    float m  = fmaxf(m0, m1);
    float w0 = exp2f(m0 - m), w1 = exp2f(m1 - m);
    float invl = 1.0f / (w0 * l0 + w1 * l1);
    w0 *= invl; w1 *= invl;

    union { uint2 d; u16 u[4]; } a, c, r;
    a.d = *(const uint2*)&Op[rbase * 64 + fq * 4];
    c.d = *(const uint2*)&Op[(rbase + BHQ) * 64 + fq * 4];
#pragma unroll
    for (int i = 0; i < 4; i++)
        r.u[i] = f2bf(w0 * bf2f(a.u[i]) + w1 * bf2f(c.u[i]));
    *(uint2*)&ctx[((size_t)q * BATCH + b) * DMODEL + h * DH + fq * 4] = r.d;
}

// ---------------- launch ------------------------------------------------------

extern "C" void kernel_launch(void* const* d_in, const int* in_sizes, int n_in,
                              void* d_out, int out_size, void* d_ws, size_t ws_size,
                              hipStream_t stream) {
    const float* x     = (const float*)d_in[0];
    const float* W_qkv = (const float*)d_in[1];
    const float* b_qkv = (const float*)d_in[2];
    const float* W_out = (const float*)d_in[3];
    const float* b_out = (const float*)d_in[4];
    float* out = (float*)d_out;

    char* ws = (char*)d_ws;
    u16* xb     = (u16*)(ws + 0);                    //  8 MB  [4096][1024]
    u16* wqkv_t = (u16*)(ws + (8u  << 20));          //  6 MB  [3072][1024]
    u16* wout_t = (u16*)(ws + (14u << 20));          //  2 MB  [1024][1024]
    u16* Qb     = (u16*)(ws + (16u << 20));          //  8 MB  [32][2048][64]
    u16* Kb     = (u16*)(ws + (24u << 20));          //  8 MB
    u16* Vt     = (u16*)(ws + (32u << 20));          //  8 MB  [32][64][2048]
    float* Mp   = (float*)(ws + (40u << 20));        // 512 KB [2][32][2048]
    float* Lp   = (float*)(ws + (40u << 20) + (512u << 10));
    u16* ctx    = xb;                                // reuse (xb dead after GEMM1)
    u16* Op     = (u16*)d_out;                       // 16 MB scratch, exactly out bytes;
                                                     // overwritten by gemm<1> at the end

    cvt4_kernel <<<(M_ROWS * DMODEL / 4) / 256, 256, 0, stream>>>(x, xb, M_ROWS * DMODEL / 4);
    cvt_t_kernel<<<dim3(N_QKV / 32, DMODEL / 32), 256, 0, stream>>>(W_qkv, wqkv_t, DMODEL, N_QKV);
    cvt_t_kernel<<<dim3(DMODEL / 32, DMODEL / 32), 256, 0, stream>>>(W_out, wout_t, DMODEL, DMODEL);

    gemm_kernel<0><<<dim3(N_QKV / 128, M_ROWS / 128), 256, 0, stream>>>(
        xb, wqkv_t, b_qkv, Qb, Kb, Vt, nullptr, M_ROWS, N_QKV, DMODEL);

    attn_kernel<<<dim3(BATCH * NH, T_SEQ / 128, 2), 256, 0, stream>>>(Qb, Kb, Vt, Op, Mp, Lp);

    merge_kernel<<<(BHQ * 16) / 256, 256, 0, stream>>>(Op, Mp, Lp, ctx);

    gemm_kernel<1><<<dim3(DMODEL / 128, M_ROWS / 128), 256, 0, stream>>>(
        ctx, wout_t, b_out, nullptr, nullptr, nullptr, out, M_ROWS, DMODEL, DMODEL);
}